// Round 1
// 436.521 us; speedup vs baseline: 1.4945x; 1.4945x over previous
//
#include <hip/hip_runtime.h>
#include <hip/hip_bf16.h>
#include <stdint.h>

typedef __bf16 bf16;
typedef __attribute__((ext_vector_type(8))) __bf16 bf16x8;
typedef __attribute__((ext_vector_type(8))) unsigned short u16x8;
typedef __attribute__((ext_vector_type(4))) float f32x4;

#define L_SEQ 2048
#define C_DIM 2048
#define NBATCH 2
#define M_ROWS (NBATCH * L_SEQ)   // 4096
#define DH 128
#define NHEAD 16
#define WINSZ 256

__device__ __forceinline__ float san(float v, float s) {
    return ((__float_as_uint(v) & 0x7f800000u) == 0x7f800000u) ? s : v;
}

__device__ __forceinline__ bf16x8 pack8(float4 lo, float4 hi) {
    bf16x8 v;
    v[0] = (bf16)lo.x; v[1] = (bf16)lo.y; v[2] = (bf16)lo.z; v[3] = (bf16)lo.w;
    v[4] = (bf16)hi.x; v[5] = (bf16)hi.y; v[6] = (bf16)hi.z; v[7] = (bf16)hi.w;
    return v;
}

// ---------------------------------------------------------------------------
// GEMM (NT): Out[m][n] = sum_k A[m][k]*W[n][k] + bias[n]   (unchanged)
// ---------------------------------------------------------------------------
template <bool AF32, bool OUTF32>
__global__ __launch_bounds__(256)
void gemm_bt_bias(const void* __restrict__ Ap,
                  const float* __restrict__ W0, const float* __restrict__ b0, void* O0,
                  const float* __restrict__ W1, const float* __restrict__ b1, void* O1,
                  const float* __restrict__ W2, const float* __restrict__ b2, void* O2,
                  float snt)
{
    const int K = C_DIM, N = C_DIM;
    const float* W = W0; const float* bias = b0; void* Out = O0;
    if (blockIdx.z == 1)      { W = W1; bias = b1; Out = O1; }
    else if (blockIdx.z == 2) { W = W2; bias = b2; Out = O2; }

    __shared__ bf16 As[128 * 32];
    __shared__ bf16 Bs[128 * 32];

    const int tid  = threadIdx.x;
    const int lane = tid & 63;
    const int m0 = blockIdx.x * 128;
    const int n0 = blockIdx.y * 128;

    const int wave = tid >> 6;
    const int wm = (wave >> 1) * 64;
    const int wn = (wave & 1) * 64;

    const int srow = tid >> 2;         // 0..63
    const int scol = (tid & 3) * 8;    // 0/8/16/24

    f32x4 acc[4][4] = {};

    const int fr = lane & 15;
    const int fq = (lane >> 4) * 8;

    for (int k0 = 0; k0 < K; k0 += 32) {
        bf16x8 ra[2], rb[2];
        #pragma unroll
        for (int p = 0; p < 2; p++) {
            const size_t aoff = (size_t)(m0 + p * 64 + srow) * K + k0 + scol;
            if (AF32) {
                const float* A = (const float*)Ap;
                float4 lo = *(const float4*)(A + aoff);
                float4 hi = *(const float4*)(A + aoff + 4);
                ra[p] = pack8(lo, hi);
            } else {
                const bf16* A = (const bf16*)Ap;
                ra[p] = *(const bf16x8*)(A + aoff);
            }
            const size_t boff = (size_t)(n0 + p * 64 + srow) * K + k0 + scol;
            float4 wlo = *(const float4*)(W + boff);
            float4 whi = *(const float4*)(W + boff + 4);
            rb[p] = pack8(wlo, whi);
        }
        __syncthreads();
        #pragma unroll
        for (int p = 0; p < 2; p++) {
            *(bf16x8*)&As[(p * 64 + srow) * 32 + scol] = ra[p];
            *(bf16x8*)&Bs[(p * 64 + srow) * 32 + scol] = rb[p];
        }
        __syncthreads();

        bf16x8 af[4], bfr[4];
        #pragma unroll
        for (int s = 0; s < 4; s++)
            af[s] = *(const bf16x8*)&As[(wm + s * 16 + fr) * 32 + fq];
        #pragma unroll
        for (int s = 0; s < 4; s++)
            bfr[s] = *(const bf16x8*)&Bs[(wn + s * 16 + fr) * 32 + fq];
        #pragma unroll
        for (int sm = 0; sm < 4; sm++)
            #pragma unroll
            for (int sn = 0; sn < 4; sn++)
                acc[sm][sn] = __builtin_amdgcn_mfma_f32_16x16x32_bf16(af[sm], bfr[sn], acc[sm][sn], 0, 0, 0);
    }

    const int r0 = (lane >> 4) * 4;
    const int cn = lane & 15;
    #pragma unroll
    for (int sn = 0; sn < 4; sn++) {
        const int n = n0 + wn + sn * 16 + cn;
        const float bv = bias[n];
        #pragma unroll
        for (int sm = 0; sm < 4; sm++) {
            const int m = m0 + wm + sm * 16 + r0;
            #pragma unroll
            for (int r = 0; r < 4; r++) {
                const float v = san(acc[sm][sn][r] + bv, snt);
                if (OUTF32) ((float*)Out)[(size_t)(m + r) * N + n] = v;
                else        ((bf16*)Out)[(size_t)(m + r) * N + n] = (bf16)v;
            }
        }
    }
}

// ---------------------------------------------------------------------------
// Sliding-window causal attention, MFMA version. WIN=256, D=128, bf16 in/out.
// 64-query tile per block, 4 waves (each owns 16 query rows), 5 K-blocks of 64.
// QK^T and PV via mfma_f32_16x16x32_bf16.
//  - Ks  [64][128] row-major, XOR swizzle byte^=(row&7)<<4 (G4 fix for 256B rows)
//  - Vt  [128][64] = V^T, pair-packed b32 writes, swizzle ((d&7)^((d>>3)&7))<<4
//    (derived: write banks = p + 4*(j^(c&7)) -> 32 distinct; read at b128 floor)
//  - Ps  [64][64] wave-private strip (rows w*16..w*16+15): no extra barrier
//    needed between P write (C-layout) and P read (A-frag layout).
// C/D layout: col=lane&15, row=(lane>>4)*4+reg (m89-verified).
// A/B frag layout: row/col=lane&15, k=(lane>>4)*8+j (matches verified GEMM).
// ---------------------------------------------------------------------------

#define SWZK(r, byteoff) ((((r) * 256) + (byteoff)) ^ (((r) & 7) << 4))
#define SWZV(d, byteoff) ((((d) * 128) + (byteoff)) ^ (((((d) & 7) ^ (((d) >> 3) & 7))) << 4))
#define SWZP(r, byteoff) ((((r) * 128) + (byteoff)) ^ (((r) & 7) << 4))

__global__ __launch_bounds__(256)
void swa_attn(const bf16* __restrict__ Q, const bf16* __restrict__ Kp,
              const bf16* __restrict__ V, bf16* __restrict__ Oattn, float snt)
{
    __shared__ bf16 Ks[64 * 128];   // 16 KB
    __shared__ bf16 Vt[128 * 64];   // 16 KB (transposed V)
    __shared__ bf16 Ps[64 * 64];    // 8 KB

    const int tid  = threadIdx.x;
    const int lane = tid & 63;
    const int w    = tid >> 6;          // wave 0..3
    const int q0 = blockIdx.x * 64;
    const int h  = blockIdx.y;
    const int b  = blockIdx.z;
    const size_t base = (size_t)b * L_SEQ * C_DIM + (size_t)h * DH;

    const int fr  = lane & 15;
    const int g   = lane >> 4;          // 0..3
    const int fq8 = g * 8;

    // Q fragments held in registers across all K-blocks (A-operand layout)
    bf16x8 qf[4];
    {
        const bf16* qrow = Q + base + (size_t)(q0 + w * 16 + fr) * C_DIM;
        #pragma unroll
        for (int kk = 0; kk < 4; kk++)
            qf[kk] = *(const bf16x8*)(qrow + kk * 32 + fq8);
    }

    const int rl0 = g * 4;                 // first C/D row this lane owns (in-wave)
    const int ig  = q0 + w * 16 + rl0;     // global query row for reg 0
    const float scale = 0.08838834764831845f;

    float m_run[4], l_run[4];
    #pragma unroll
    for (int r = 0; r < 4; r++) { m_run[r] = -1e30f; l_run[r] = 0.0f; }
    f32x4 Oacc[8] = {};

    // staging coordinates
    const int krr = tid >> 4;            // 0..15  (K row within 16-row group)
    const int kcc = (tid & 15) * 8;      // K dim chunk
    const int vc  = tid & 15;            // V d-chunk index
    const int vd0 = vc * 8;
    const int vpb = tid >> 4;            // 0..15 key-pair base

    for (int kb = 0; kb < 5; kb++) {
        const int s = q0 - 256 + kb * 64;
        if (s < 0) continue;             // block-uniform

        __syncthreads();                 // prev iter's LDS reads done

        // ---- stage K rows (swizzled row-major) ----
        #pragma unroll
        for (int p = 0; p < 4; p++) {
            const int r = p * 16 + krr;
            const uint4 kv = *(const uint4*)(Kp + base + (size_t)(s + r) * C_DIM + kcc);
            *(uint4*)((char*)Ks + SWZK(r, kcc * 2)) = kv;
        }
        // ---- stage V transposed (pair-packed b32 writes) ----
        #pragma unroll
        for (int it = 0; it < 2; it++) {
            const int p = vpb + it * 16;             // key pair 0..31
            const bf16* vr = V + base + (size_t)(s + 2 * p) * C_DIM + vd0;
            const u16x8 va = *(const u16x8*)vr;
            const u16x8 vb = *(const u16x8*)(vr + C_DIM);
            #pragma unroll
            for (int j = 0; j < 8; j++) {
                const uint32_t val = (uint32_t)va[j] | ((uint32_t)vb[j] << 16);
                *(uint32_t*)((char*)Vt + SWZV(vd0 + j, 4 * p)) = val;
            }
        }
        __syncthreads();

        // ---- QK^T: S[16 rows][64 cols] per wave ----
        f32x4 sacc[4] = {};
        __builtin_amdgcn_s_setprio(1);
        #pragma unroll
        for (int kk = 0; kk < 4; kk++) {
            #pragma unroll
            for (int t = 0; t < 4; t++) {
                const bf16x8 kf = *(const bf16x8*)((char*)Ks + SWZK(t * 16 + fr, (kk * 32 + fq8) * 2));
                sacc[t] = __builtin_amdgcn_mfma_f32_16x16x32_bf16(qf[kk], kf, sacc[t], 0, 0, 0);
            }
        }
        __builtin_amdgcn_s_setprio(0);

        // ---- masked online softmax, per owned row ----
        float alpha[4];
        #pragma unroll
        for (int r = 0; r < 4; r++) {
            const int iq = ig + r;
            float p4[4];
            float bm = -1e30f;
            #pragma unroll
            for (int t = 0; t < 4; t++) {
                const int j = s + t * 16 + fr;
                const bool allow = (j <= iq) && (j > iq - WINSZ);
                p4[t] = allow ? sacc[t][r] * scale : -1e30f;
                bm = fmaxf(bm, p4[t]);
            }
            bm = fmaxf(bm, __shfl_xor(bm, 1, 64));
            bm = fmaxf(bm, __shfl_xor(bm, 2, 64));
            bm = fmaxf(bm, __shfl_xor(bm, 4, 64));
            bm = fmaxf(bm, __shfl_xor(bm, 8, 64));
            const float m_new = fmaxf(m_run[r], bm);
            alpha[r] = __expf(m_run[r] - m_new);
            m_run[r] = m_new;
            float ps = 0.0f;
            #pragma unroll
            for (int t = 0; t < 4; t++) {
                const float e = (p4[t] > -1e29f) ? __expf(p4[t] - m_new) : 0.0f;
                p4[t] = e;
                ps += e;
            }
            ps += __shfl_xor(ps, 1, 64);
            ps += __shfl_xor(ps, 2, 64);
            ps += __shfl_xor(ps, 4, 64);
            ps += __shfl_xor(ps, 8, 64);
            l_run[r] = l_run[r] * alpha[r] + ps;

            // write P row to wave-private LDS strip (C-layout -> row-major)
            const int prow = w * 16 + rl0 + r;
            #pragma unroll
            for (int t = 0; t < 4; t++)
                *(bf16*)((char*)Ps + SWZP(prow, (t * 16 + fr) * 2)) = (bf16)p4[t];
        }

        // rescale O accumulator (row r of each fragment scaled by alpha[r])
        #pragma unroll
        for (int t = 0; t < 8; t++)
            #pragma unroll
            for (int r = 0; r < 4; r++)
                Oacc[t][r] *= alpha[r];

        // ---- PV: O[16 rows][128 dims] += P[16][64] * V[64][128] ----
        __builtin_amdgcn_s_setprio(1);
        #pragma unroll
        for (int kk = 0; kk < 2; kk++) {
            const bf16x8 pa = *(const bf16x8*)((char*)Ps + SWZP(w * 16 + fr, (kk * 32 + fq8) * 2));
            #pragma unroll
            for (int t = 0; t < 8; t++) {
                const bf16x8 vf = *(const bf16x8*)((char*)Vt + SWZV(t * 16 + fr, (kk * 32 + fq8) * 2));
                Oacc[t] = __builtin_amdgcn_mfma_f32_16x16x32_bf16(pa, vf, Oacc[t], 0, 0, 0);
            }
        }
        __builtin_amdgcn_s_setprio(0);
    }

    // ---- epilogue: O = Oacc / l ----
    bf16* ob = Oattn + base;
    #pragma unroll
    for (int r = 0; r < 4; r++) {
        const float inv_l = 1.0f / l_run[r];
        const size_t ro = (size_t)(q0 + w * 16 + rl0 + r) * C_DIM;
        #pragma unroll
        for (int t = 0; t < 8; t++)
            ob[ro + t * 16 + fr] = (bf16)san(Oacc[t][r] * inv_l, snt);
    }
}

// layout-surprise signal (fp32 output)
__global__ void fill_signal(float* out, int n, float v) {
    for (int i = blockIdx.x * blockDim.x + threadIdx.x; i < n; i += gridDim.x * blockDim.x)
        out[i] = v;
}

// ---------------------------------------------------------------------------
extern "C" void kernel_launch(void* const* d_in, const int* in_sizes, int n_in,
                              void* d_out, int out_size, void* d_ws, size_t ws_size,
                              hipStream_t stream) {
    const size_t sz      = (size_t)M_ROWS * C_DIM;   // 8388608 elements
    const size_t bfbytes = sz * sizeof(bf16);        // 16.78 MB per bf16 buffer

    const int expn[9] = {8388608, 4194304, 2048, 4194304, 2048,
                         4194304, 2048, 4194304, 2048};
    float sig = 0.0f;
    if (n_in != 9) sig = 1100.0f;
    else {
        for (int i = 0; i < 9; i++)
            if (in_sizes[i] != expn[i]) { sig = 1200.0f + 100.0f * i; break; }
    }
    if (sig == 0.0f && out_size != (int)sz) sig = 2100.0f;
    if (sig == 0.0f && ws_size < 2 * bfbytes) sig = 3000.0f + 10.0f * (float)(ws_size >> 20);
    if (sig != 0.0f) {
        fill_signal<<<512, 256, 0, stream>>>((float*)d_out, (int)sz, sig);
        return;
    }

    const float* x  = (const float*)d_in[0];
    const float* Wq = (const float*)d_in[1];
    const float* bq = (const float*)d_in[2];
    const float* Wk = (const float*)d_in[3];
    const float* bk = (const float*)d_in[4];
    const float* Wv = (const float*)d_in[5];
    const float* bv = (const float*)d_in[6];
    const float* Wo = (const float*)d_in[7];
    const float* bo = (const float*)d_in[8];

    bf16*  kws   = (bf16*)d_ws;        // K (bf16), later reused for O_att
    bf16*  vws   = kws + sz;           // V (bf16)
    bf16*  qscr  = (bf16*)d_out;       // Q / O_att (bf16) in d_out's first half
    float* out32 = (float*)d_out;      // final fp32 output

    // 1) QKV projections (fp32 in, bf16 out)
    gemm_bt_bias<true, false><<<dim3(32, 16, 3), 256, 0, stream>>>(
        (const void*)x, Wq, bq, (void*)qscr, Wk, bk, (void*)kws,
        Wv, bv, (void*)vws, 111.0f);

    // 2) attention (MFMA flash), O_att written in place over Q (bf16)
    swa_attn<<<dim3(L_SEQ / 64, NHEAD, NBATCH), 256, 0, stream>>>(
        qscr, kws, vws, qscr, 222.0f);

    // 3) move O_att (bf16) into the dead K region before fp32 overwrite
    hipMemcpyAsync(kws, qscr, bfbytes, hipMemcpyDeviceToDevice, stream);

    // 4) output projection (bf16 in, fp32 out)
    gemm_bt_bias<false, true><<<dim3(32, 16, 1), 256, 0, stream>>>(
        (const void*)kws, Wo, bo, (void*)out32, Wo, bo, (void*)out32,
        Wo, bo, (void*)out32, 444.0f);
}

// Round 2
// 386.632 us; speedup vs baseline: 1.6873x; 1.1290x over previous
//
#include <hip/hip_runtime.h>
#include <hip/hip_bf16.h>
#include <stdint.h>

typedef __bf16 bf16;
typedef __attribute__((ext_vector_type(8))) __bf16 bf16x8;
typedef __attribute__((ext_vector_type(8))) unsigned short u16x8;
typedef __attribute__((ext_vector_type(4))) float f32x4;

#define L_SEQ 2048
#define C_DIM 2048
#define NBATCH 2
#define M_ROWS (NBATCH * L_SEQ)   // 4096
#define DH 128
#define NHEAD 16
#define WINSZ 256

__device__ __forceinline__ float san(float v, float s) {
    return ((__float_as_uint(v) & 0x7f800000u) == 0x7f800000u) ? s : v;
}

__device__ __forceinline__ bf16x8 pack8(float4 lo, float4 hi) {
    bf16x8 v;
    v[0] = (bf16)lo.x; v[1] = (bf16)lo.y; v[2] = (bf16)lo.z; v[3] = (bf16)lo.w;
    v[4] = (bf16)hi.x; v[5] = (bf16)hi.y; v[6] = (bf16)hi.z; v[7] = (bf16)hi.w;
    return v;
}

// async global->LDS, 16B per lane; LDS dest = wave-uniform base + lane*16
typedef const __attribute__((address_space(1))) void g_void;
typedef __attribute__((address_space(3))) void l_void;
__device__ __forceinline__ void glds16(const void* g, void* l) {
    __builtin_amdgcn_global_load_lds((g_void*)g, (l_void*)l, 16, 0, 0);
}

// ---------------------------------------------------------------------------
// SLOW-PATH GEMM (NT, reg-staged, fp32 or bf16 A) — verbatim from r1 (436 us)
// ---------------------------------------------------------------------------
template <bool AF32, bool OUTF32>
__global__ __launch_bounds__(256)
void gemm_bt_bias(const void* __restrict__ Ap,
                  const float* __restrict__ W0, const float* __restrict__ b0, void* O0,
                  const float* __restrict__ W1, const float* __restrict__ b1, void* O1,
                  const float* __restrict__ W2, const float* __restrict__ b2, void* O2,
                  float snt)
{
    const int K = C_DIM, N = C_DIM;
    const float* W = W0; const float* bias = b0; void* Out = O0;
    if (blockIdx.z == 1)      { W = W1; bias = b1; Out = O1; }
    else if (blockIdx.z == 2) { W = W2; bias = b2; Out = O2; }

    __shared__ bf16 As[128 * 32];
    __shared__ bf16 Bs[128 * 32];

    const int tid  = threadIdx.x;
    const int lane = tid & 63;
    const int m0 = blockIdx.x * 128;
    const int n0 = blockIdx.y * 128;

    const int wave = tid >> 6;
    const int wm = (wave >> 1) * 64;
    const int wn = (wave & 1) * 64;

    const int srow = tid >> 2;
    const int scol = (tid & 3) * 8;

    f32x4 acc[4][4] = {};

    const int fr = lane & 15;
    const int fq = (lane >> 4) * 8;

    for (int k0 = 0; k0 < K; k0 += 32) {
        bf16x8 ra[2], rb[2];
        #pragma unroll
        for (int p = 0; p < 2; p++) {
            const size_t aoff = (size_t)(m0 + p * 64 + srow) * K + k0 + scol;
            if (AF32) {
                const float* A = (const float*)Ap;
                float4 lo = *(const float4*)(A + aoff);
                float4 hi = *(const float4*)(A + aoff + 4);
                ra[p] = pack8(lo, hi);
            } else {
                const bf16* A = (const bf16*)Ap;
                ra[p] = *(const bf16x8*)(A + aoff);
            }
            const size_t boff = (size_t)(n0 + p * 64 + srow) * K + k0 + scol;
            float4 wlo = *(const float4*)(W + boff);
            float4 whi = *(const float4*)(W + boff + 4);
            rb[p] = pack8(wlo, whi);
        }
        __syncthreads();
        #pragma unroll
        for (int p = 0; p < 2; p++) {
            *(bf16x8*)&As[(p * 64 + srow) * 32 + scol] = ra[p];
            *(bf16x8*)&Bs[(p * 64 + srow) * 32 + scol] = rb[p];
        }
        __syncthreads();

        bf16x8 af[4], bfr[4];
        #pragma unroll
        for (int s = 0; s < 4; s++)
            af[s] = *(const bf16x8*)&As[(wm + s * 16 + fr) * 32 + fq];
        #pragma unroll
        for (int s = 0; s < 4; s++)
            bfr[s] = *(const bf16x8*)&Bs[(wn + s * 16 + fr) * 32 + fq];
        #pragma unroll
        for (int sm = 0; sm < 4; sm++)
            #pragma unroll
            for (int sn = 0; sn < 4; sn++)
                acc[sm][sn] = __builtin_amdgcn_mfma_f32_16x16x32_bf16(af[sm], bfr[sn], acc[sm][sn], 0, 0, 0);
    }

    const int r0 = (lane >> 4) * 4;
    const int cn = lane & 15;
    #pragma unroll
    for (int sn = 0; sn < 4; sn++) {
        const int n = n0 + wn + sn * 16 + cn;
        const float bv = bias[n];
        #pragma unroll
        for (int sm = 0; sm < 4; sm++) {
            const int m = m0 + wm + sm * 16 + r0;
            #pragma unroll
            for (int r = 0; r < 4; r++) {
                const float v = san(acc[sm][sn][r] + bv, snt);
                if (OUTF32) ((float*)Out)[(size_t)(m + r) * N + n] = v;
                else        ((bf16*)Out)[(size_t)(m + r) * N + n] = (bf16)v;
            }
        }
    }
}

// ---------------------------------------------------------------------------
// FAST-PATH GEMM (NT): bf16 A and bf16 W, m97-structure: 128x128 tile, BK=32,
// global_load_lds width=16 (linear LDS), 2-barrier loop, 4 waves x 4x4 MFMA.
// XCD-bijective block swizzle (512 blocks/slice, 512%8==0).
// ---------------------------------------------------------------------------
template <bool OUTF32>
__global__ __launch_bounds__(256)
void gemm_bb_bias(const bf16* __restrict__ A,
                  const bf16* __restrict__ W0, const float* __restrict__ b0, void* O0,
                  const bf16* __restrict__ W1, const float* __restrict__ b1, void* O1,
                  const bf16* __restrict__ W2, const float* __restrict__ b2, void* O2,
                  float snt)
{
    const int K = C_DIM, N = C_DIM;
    const bf16* W = W0; const float* bias = b0; void* Out = O0;
    if (blockIdx.z == 1)      { W = W1; bias = b1; Out = O1; }
    else if (blockIdx.z == 2) { W = W2; bias = b2; Out = O2; }

    __shared__ bf16 As[128 * 32];   // 8 KB, linear (required by global_load_lds)
    __shared__ bf16 Bs[128 * 32];   // 8 KB

    const int tid  = threadIdx.x;
    const int lane = tid & 63;
    const int wv   = tid >> 6;

    // XCD-aware bijective swizzle within the z-slice (nwg = 32*16 = 512)
    int wg = blockIdx.x + (int)gridDim.x * blockIdx.y;
    wg = (wg & 7) * 64 + (wg >> 3);
    const int m0 = (wg & 31) * 128;
    const int n0 = (wg >> 5) * 128;

    // staging coords: thread t loads 16B at row t>>2, col (t&3)*8
    const int grow = tid >> 2;
    const int gcol = (tid & 3) * 8;
    char* const asw = (char*)As + wv * 1024;   // wave-uniform LDS bases
    char* const bsw = (char*)Bs + wv * 1024;

    f32x4 acc[4][4] = {};

    const int fr = lane & 15;
    const int fq = (lane >> 4) * 8;
    const int wm = (wv >> 1) * 64;
    const int wn = (wv & 1) * 64;

    const bf16* arow = A + (size_t)(m0 + grow) * K + gcol;
    const bf16* brow = W + (size_t)(n0 + grow) * K + gcol;

    for (int k0 = 0; k0 < K; k0 += 32) {
        __syncthreads();   // previous iter's LDS reads complete
        glds16(arow + k0,               asw);
        glds16(arow + k0 + 64 * K,      asw + 4096);
        glds16(brow + k0,               bsw);
        glds16(brow + k0 + 64 * K,      bsw + 4096);
        __syncthreads();   // drains vmcnt: staged data visible

        bf16x8 af[4], bfr[4];
        #pragma unroll
        for (int s = 0; s < 4; s++)
            af[s] = *(const bf16x8*)&As[(wm + s * 16 + fr) * 32 + fq];
        #pragma unroll
        for (int s = 0; s < 4; s++)
            bfr[s] = *(const bf16x8*)&Bs[(wn + s * 16 + fr) * 32 + fq];
        #pragma unroll
        for (int sm = 0; sm < 4; sm++)
            #pragma unroll
            for (int sn = 0; sn < 4; sn++)
                acc[sm][sn] = __builtin_amdgcn_mfma_f32_16x16x32_bf16(af[sm], bfr[sn], acc[sm][sn], 0, 0, 0);
    }

    const int r0 = (lane >> 4) * 4;
    const int cn = lane & 15;
    #pragma unroll
    for (int sn = 0; sn < 4; sn++) {
        const int n = n0 + wn + sn * 16 + cn;
        const float bv = bias[n];
        #pragma unroll
        for (int sm = 0; sm < 4; sm++) {
            const int m = m0 + wm + sm * 16 + r0;
            #pragma unroll
            for (int r = 0; r < 4; r++) {
                const float v = san(acc[sm][sn][r] + bv, snt);
                if (OUTF32) ((float*)Out)[(size_t)(m + r) * N + n] = v;
                else        ((bf16*)Out)[(size_t)(m + r) * N + n] = (bf16)v;
            }
        }
    }
}

// ---------------------------------------------------------------------------
// one-shot fp32 -> bf16 conversion: seg 0 = x (8.4M), segs 1..4 = W (4.2M each)
// ---------------------------------------------------------------------------
__global__ __launch_bounds__(256)
void cvt_f32_bf16(const float* __restrict__ s0, bf16* __restrict__ d0,
                  const float* __restrict__ s1, bf16* __restrict__ d1,
                  const float* __restrict__ s2, bf16* __restrict__ d2,
                  const float* __restrict__ s3, bf16* __restrict__ d3,
                  const float* __restrict__ s4, bf16* __restrict__ d4)
{
    const float* s; bf16* d; int n;
    switch (blockIdx.y) {
        case 0:  s = s0; d = d0; n = M_ROWS * C_DIM; break;
        case 1:  s = s1; d = d1; n = C_DIM * C_DIM; break;
        case 2:  s = s2; d = d2; n = C_DIM * C_DIM; break;
        case 3:  s = s3; d = d3; n = C_DIM * C_DIM; break;
        default: s = s4; d = d4; n = C_DIM * C_DIM; break;
    }
    const int nv = n >> 3;
    const int stride = (int)gridDim.x * 256;
    for (int i = blockIdx.x * 256 + threadIdx.x; i < nv; i += stride) {
        const float4 lo = *(const float4*)(s + (size_t)i * 8);
        const float4 hi = *(const float4*)(s + (size_t)i * 8 + 4);
        *(bf16x8*)(d + (size_t)i * 8) = pack8(lo, hi);
    }
}

// ---------------------------------------------------------------------------
// Sliding-window causal attention, MFMA flash (verified r1). Unchanged.
// ---------------------------------------------------------------------------
#define SWZK(r, byteoff) ((((r) * 256) + (byteoff)) ^ (((r) & 7) << 4))
#define SWZV(d, byteoff) ((((d) * 128) + (byteoff)) ^ (((((d) & 7) ^ (((d) >> 3) & 7))) << 4))
#define SWZP(r, byteoff) ((((r) * 128) + (byteoff)) ^ (((r) & 7) << 4))

__global__ __launch_bounds__(256)
void swa_attn(const bf16* __restrict__ Q, const bf16* __restrict__ Kp,
              const bf16* __restrict__ V, bf16* __restrict__ Oattn, float snt)
{
    __shared__ bf16 Ks[64 * 128];
    __shared__ bf16 Vt[128 * 64];
    __shared__ bf16 Ps[64 * 64];

    const int tid  = threadIdx.x;
    const int lane = tid & 63;
    const int w    = tid >> 6;
    const int q0 = blockIdx.x * 64;
    const int h  = blockIdx.y;
    const int b  = blockIdx.z;
    const size_t base = (size_t)b * L_SEQ * C_DIM + (size_t)h * DH;

    const int fr  = lane & 15;
    const int g   = lane >> 4;
    const int fq8 = g * 8;

    bf16x8 qf[4];
    {
        const bf16* qrow = Q + base + (size_t)(q0 + w * 16 + fr) * C_DIM;
        #pragma unroll
        for (int kk = 0; kk < 4; kk++)
            qf[kk] = *(const bf16x8*)(qrow + kk * 32 + fq8);
    }

    const int rl0 = g * 4;
    const int ig  = q0 + w * 16 + rl0;
    const float scale = 0.08838834764831845f;

    float m_run[4], l_run[4];
    #pragma unroll
    for (int r = 0; r < 4; r++) { m_run[r] = -1e30f; l_run[r] = 0.0f; }
    f32x4 Oacc[8] = {};

    const int krr = tid >> 4;
    const int kcc = (tid & 15) * 8;
    const int vc  = tid & 15;
    const int vd0 = vc * 8;
    const int vpb = tid >> 4;

    for (int kb = 0; kb < 5; kb++) {
        const int s = q0 - 256 + kb * 64;
        if (s < 0) continue;

        __syncthreads();

        #pragma unroll
        for (int p = 0; p < 4; p++) {
            const int r = p * 16 + krr;
            const uint4 kv = *(const uint4*)(Kp + base + (size_t)(s + r) * C_DIM + kcc);
            *(uint4*)((char*)Ks + SWZK(r, kcc * 2)) = kv;
        }
        #pragma unroll
        for (int it = 0; it < 2; it++) {
            const int p = vpb + it * 16;
            const bf16* vr = V + base + (size_t)(s + 2 * p) * C_DIM + vd0;
            const u16x8 va = *(const u16x8*)vr;
            const u16x8 vb = *(const u16x8*)(vr + C_DIM);
            #pragma unroll
            for (int j = 0; j < 8; j++) {
                const uint32_t val = (uint32_t)va[j] | ((uint32_t)vb[j] << 16);
                *(uint32_t*)((char*)Vt + SWZV(vd0 + j, 4 * p)) = val;
            }
        }
        __syncthreads();

        f32x4 sacc[4] = {};
        __builtin_amdgcn_s_setprio(1);
        #pragma unroll
        for (int kk = 0; kk < 4; kk++) {
            #pragma unroll
            for (int t = 0; t < 4; t++) {
                const bf16x8 kf = *(const bf16x8*)((char*)Ks + SWZK(t * 16 + fr, (kk * 32 + fq8) * 2));
                sacc[t] = __builtin_amdgcn_mfma_f32_16x16x32_bf16(qf[kk], kf, sacc[t], 0, 0, 0);
            }
        }
        __builtin_amdgcn_s_setprio(0);

        float alpha[4];
        #pragma unroll
        for (int r = 0; r < 4; r++) {
            const int iq = ig + r;
            float p4[4];
            float bm = -1e30f;
            #pragma unroll
            for (int t = 0; t < 4; t++) {
                const int j = s + t * 16 + fr;
                const bool allow = (j <= iq) && (j > iq - WINSZ);
                p4[t] = allow ? sacc[t][r] * scale : -1e30f;
                bm = fmaxf(bm, p4[t]);
            }
            bm = fmaxf(bm, __shfl_xor(bm, 1, 64));
            bm = fmaxf(bm, __shfl_xor(bm, 2, 64));
            bm = fmaxf(bm, __shfl_xor(bm, 4, 64));
            bm = fmaxf(bm, __shfl_xor(bm, 8, 64));
            const float m_new = fmaxf(m_run[r], bm);
            alpha[r] = __expf(m_run[r] - m_new);
            m_run[r] = m_new;
            float ps = 0.0f;
            #pragma unroll
            for (int t = 0; t < 4; t++) {
                const float e = (p4[t] > -1e29f) ? __expf(p4[t] - m_new) : 0.0f;
                p4[t] = e;
                ps += e;
            }
            ps += __shfl_xor(ps, 1, 64);
            ps += __shfl_xor(ps, 2, 64);
            ps += __shfl_xor(ps, 4, 64);
            ps += __shfl_xor(ps, 8, 64);
            l_run[r] = l_run[r] * alpha[r] + ps;

            const int prow = w * 16 + rl0 + r;
            #pragma unroll
            for (int t = 0; t < 4; t++)
                *(bf16*)((char*)Ps + SWZP(prow, (t * 16 + fr) * 2)) = (bf16)p4[t];
        }

        #pragma unroll
        for (int t = 0; t < 8; t++)
            #pragma unroll
            for (int r = 0; r < 4; r++)
                Oacc[t][r] *= alpha[r];

        __builtin_amdgcn_s_setprio(1);
        #pragma unroll
        for (int kk = 0; kk < 2; kk++) {
            const bf16x8 pa = *(const bf16x8*)((char*)Ps + SWZP(w * 16 + fr, (kk * 32 + fq8) * 2));
            #pragma unroll
            for (int t = 0; t < 8; t++) {
                const bf16x8 vf = *(const bf16x8*)((char*)Vt + SWZV(t * 16 + fr, (kk * 32 + fq8) * 2));
                Oacc[t] = __builtin_amdgcn_mfma_f32_16x16x32_bf16(pa, vf, Oacc[t], 0, 0, 0);
            }
        }
        __builtin_amdgcn_s_setprio(0);
    }

    bf16* ob = Oattn + base;
    #pragma unroll
    for (int r = 0; r < 4; r++) {
        const float inv_l = 1.0f / l_run[r];
        const size_t ro = (size_t)(q0 + w * 16 + rl0 + r) * C_DIM;
        #pragma unroll
        for (int t = 0; t < 8; t++)
            ob[ro + t * 16 + fr] = (bf16)san(Oacc[t][r] * inv_l, snt);
    }
}

// layout-surprise signal (fp32 output)
__global__ void fill_signal(float* out, int n, float v) {
    for (int i = blockIdx.x * blockDim.x + threadIdx.x; i < n; i += gridDim.x * blockDim.x)
        out[i] = v;
}

// ---------------------------------------------------------------------------
extern "C" void kernel_launch(void* const* d_in, const int* in_sizes, int n_in,
                              void* d_out, int out_size, void* d_ws, size_t ws_size,
                              hipStream_t stream) {
    const size_t sz      = (size_t)M_ROWS * C_DIM;   // 8388608 elements
    const size_t wsz     = (size_t)C_DIM * C_DIM;    // 4194304 elements
    const size_t bfbytes = sz * sizeof(bf16);        // 16.78 MB
    const size_t FASTNEED = 3 * sz * sizeof(bf16) + 4 * wsz * sizeof(bf16); // 80 MB

    const int expn[9] = {8388608, 4194304, 2048, 4194304, 2048,
                         4194304, 2048, 4194304, 2048};
    float sig = 0.0f;
    if (n_in != 9) sig = 1100.0f;
    else {
        for (int i = 0; i < 9; i++)
            if (in_sizes[i] != expn[i]) { sig = 1200.0f + 100.0f * i; break; }
    }
    if (sig == 0.0f && out_size != (int)sz) sig = 2100.0f;
    if (sig == 0.0f && ws_size < 2 * bfbytes) sig = 3000.0f + 10.0f * (float)(ws_size >> 20);
    if (sig != 0.0f) {
        fill_signal<<<512, 256, 0, stream>>>((float*)d_out, (int)sz, sig);
        return;
    }

    const float* x  = (const float*)d_in[0];
    const float* Wq = (const float*)d_in[1];
    const float* bq = (const float*)d_in[2];
    const float* Wk = (const float*)d_in[3];
    const float* bk = (const float*)d_in[4];
    const float* Wv = (const float*)d_in[5];
    const float* bv = (const float*)d_in[6];
    const float* Wo = (const float*)d_in[7];
    const float* bo = (const float*)d_in[8];

    if (ws_size >= FASTNEED) {
        // ---------------- fast path: pre-converted bf16 operands ----------------
        bf16* xbf = (bf16*)d_ws;          // x bf16; later reused as O_att
        bf16* kws = xbf + sz;             // K
        bf16* vws = kws + sz;             // V
        bf16* wqb = vws + sz;             // W bf16 x4
        bf16* wkb = wqb + wsz;
        bf16* wvb = wkb + wsz;
        bf16* wob = wvb + wsz;
        bf16*  qscr  = (bf16*)d_out;      // Q bf16 in d_out's first half
        float* out32 = (float*)d_out;

        // 0) fp32 -> bf16 one-shot conversions
        cvt_f32_bf16<<<dim3(2048, 5), 256, 0, stream>>>(
            x, xbf, Wq, wqb, Wk, wkb, Wv, wvb, Wo, wob);

        // 1) QKV projections (bf16 x bf16, global_load_lds path)
        gemm_bb_bias<false><<<dim3(32, 16, 3), 256, 0, stream>>>(
            xbf, wqb, bq, (void*)qscr, wkb, bk, (void*)kws,
            wvb, bv, (void*)vws, 111.0f);

        // 2) attention; O_att -> dead xbf region (no aliasing with d_out)
        swa_attn<<<dim3(L_SEQ / 64, NHEAD, NBATCH), 256, 0, stream>>>(
            qscr, kws, vws, xbf, 222.0f);

        // 3) output projection (bf16 x bf16, fp32 out), full d_out overwrite
        gemm_bb_bias<true><<<dim3(32, 16, 1), 256, 0, stream>>>(
            xbf, wob, bo, (void*)out32, wob, bo, (void*)out32,
            wob, bo, (void*)out32, 444.0f);
    } else {
        // ---------------- slow path: r1-verified flow (436 us) ----------------
        bf16*  kws   = (bf16*)d_ws;
        bf16*  vws   = kws + sz;
        bf16*  qscr  = (bf16*)d_out;
        float* out32 = (float*)d_out;

        gemm_bt_bias<true, false><<<dim3(32, 16, 3), 256, 0, stream>>>(
            (const void*)x, Wq, bq, (void*)qscr, Wk, bk, (void*)kws,
            Wv, bv, (void*)vws, 111.0f);

        swa_attn<<<dim3(L_SEQ / 64, NHEAD, NBATCH), 256, 0, stream>>>(
            qscr, kws, vws, qscr, 222.0f);

        hipMemcpyAsync(kws, qscr, bfbytes, hipMemcpyDeviceToDevice, stream);

        gemm_bt_bias<false, true><<<dim3(32, 16, 1), 256, 0, stream>>>(
            (const void*)kws, Wo, bo, (void*)out32, Wo, bo, (void*)out32,
            Wo, bo, (void*)out32, 444.0f);
    }
}

// Round 3
// 359.801 us; speedup vs baseline: 1.8132x; 1.0746x over previous
//
#include <hip/hip_runtime.h>
#include <hip/hip_bf16.h>
#include <stdint.h>

typedef __bf16 bf16;
typedef __attribute__((ext_vector_type(8))) __bf16 bf16x8;
typedef __attribute__((ext_vector_type(8))) unsigned short u16x8;
typedef __attribute__((ext_vector_type(4))) float f32x4;

#define L_SEQ 2048
#define C_DIM 2048
#define NBATCH 2
#define M_ROWS (NBATCH * L_SEQ)   // 4096
#define DH 128
#define NHEAD 16
#define WINSZ 256

__device__ __forceinline__ float san(float v, float s) {
    return ((__float_as_uint(v) & 0x7f800000u) == 0x7f800000u) ? s : v;
}

__device__ __forceinline__ bf16x8 pack8(float4 lo, float4 hi) {
    bf16x8 v;
    v[0] = (bf16)lo.x; v[1] = (bf16)lo.y; v[2] = (bf16)lo.z; v[3] = (bf16)lo.w;
    v[4] = (bf16)hi.x; v[5] = (bf16)hi.y; v[6] = (bf16)hi.z; v[7] = (bf16)hi.w;
    return v;
}

typedef const __attribute__((address_space(1))) void g_void;
typedef __attribute__((address_space(3))) void l_void;
__device__ __forceinline__ void glds16(const void* g, void* l) {
    __builtin_amdgcn_global_load_lds((g_void*)g, (l_void*)l, 16, 0, 0);
}

// ---------------------------------------------------------------------------
// SLOW-PATH GEMM (reg-staged) — fallback when workspace is small. Verified.
// ---------------------------------------------------------------------------
template <bool AF32, bool OUTF32>
__global__ __launch_bounds__(256)
void gemm_bt_bias(const void* __restrict__ Ap,
                  const float* __restrict__ W0, const float* __restrict__ b0, void* O0,
                  const float* __restrict__ W1, const float* __restrict__ b1, void* O1,
                  const float* __restrict__ W2, const float* __restrict__ b2, void* O2,
                  float snt)
{
    const int K = C_DIM, N = C_DIM;
    const float* W = W0; const float* bias = b0; void* Out = O0;
    if (blockIdx.z == 1)      { W = W1; bias = b1; Out = O1; }
    else if (blockIdx.z == 2) { W = W2; bias = b2; Out = O2; }

    __shared__ bf16 As[128 * 32];
    __shared__ bf16 Bs[128 * 32];

    const int tid  = threadIdx.x;
    const int lane = tid & 63;
    const int m0 = blockIdx.x * 128;
    const int n0 = blockIdx.y * 128;

    const int wave = tid >> 6;
    const int wm = (wave >> 1) * 64;
    const int wn = (wave & 1) * 64;

    const int srow = tid >> 2;
    const int scol = (tid & 3) * 8;

    f32x4 acc[4][4] = {};

    const int fr = lane & 15;
    const int fq = (lane >> 4) * 8;

    for (int k0 = 0; k0 < K; k0 += 32) {
        bf16x8 ra[2], rb[2];
        #pragma unroll
        for (int p = 0; p < 2; p++) {
            const size_t aoff = (size_t)(m0 + p * 64 + srow) * K + k0 + scol;
            if (AF32) {
                const float* A = (const float*)Ap;
                float4 lo = *(const float4*)(A + aoff);
                float4 hi = *(const float4*)(A + aoff + 4);
                ra[p] = pack8(lo, hi);
            } else {
                const bf16* A = (const bf16*)Ap;
                ra[p] = *(const bf16x8*)(A + aoff);
            }
            const size_t boff = (size_t)(n0 + p * 64 + srow) * K + k0 + scol;
            float4 wlo = *(const float4*)(W + boff);
            float4 whi = *(const float4*)(W + boff + 4);
            rb[p] = pack8(wlo, whi);
        }
        __syncthreads();
        #pragma unroll
        for (int p = 0; p < 2; p++) {
            *(bf16x8*)&As[(p * 64 + srow) * 32 + scol] = ra[p];
            *(bf16x8*)&Bs[(p * 64 + srow) * 32 + scol] = rb[p];
        }
        __syncthreads();

        bf16x8 af[4], bfr[4];
        #pragma unroll
        for (int s = 0; s < 4; s++)
            af[s] = *(const bf16x8*)&As[(wm + s * 16 + fr) * 32 + fq];
        #pragma unroll
        for (int s = 0; s < 4; s++)
            bfr[s] = *(const bf16x8*)&Bs[(wn + s * 16 + fr) * 32 + fq];
        #pragma unroll
        for (int sm = 0; sm < 4; sm++)
            #pragma unroll
            for (int sn = 0; sn < 4; sn++)
                acc[sm][sn] = __builtin_amdgcn_mfma_f32_16x16x32_bf16(af[sm], bfr[sn], acc[sm][sn], 0, 0, 0);
    }

    const int r0 = (lane >> 4) * 4;
    const int cn = lane & 15;
    #pragma unroll
    for (int sn = 0; sn < 4; sn++) {
        const int n = n0 + wn + sn * 16 + cn;
        const float bv = bias[n];
        #pragma unroll
        for (int sm = 0; sm < 4; sm++) {
            const int m = m0 + wm + sm * 16 + r0;
            #pragma unroll
            for (int r = 0; r < 4; r++) {
                const float v = san(acc[sm][sn][r] + bv, snt);
                if (OUTF32) ((float*)Out)[(size_t)(m + r) * N + n] = v;
                else        ((bf16*)Out)[(size_t)(m + r) * N + n] = (bf16)v;
            }
        }
    }
}

// ---------------------------------------------------------------------------
// FAST GEMM: 256x256 tile, BK=64, 8 waves (2M x 4N), 8-phase schedule with
// counted vmcnt(4), double-buffered 128KB LDS, XOR chunk-swizzle (T2) applied
// as pre-swizzled global source + swizzled ds_read (rule #21), T5 setprio.
//
// Slot map (bytes): buf d in [d*65536, +65536): A h0 [0,16K) h1 [16K,32K),
//                   B h0 [32K,48K) h1 [48K,64K). Row-major 128B rows, with
//                   chunk swizzle c ^= (row&7) on content placement.
// Stage schedule per iteration i (tiles 2i, 2i+1):
//   ph1: (2i+1).Ah0  ph2: (2i+1).Ah1  ph3: (2i+2).Bh0  ph4: (2i+2).Bh1 +vm4
//   ph5: (2i+2).Ah0  ph6: (2i+2).Ah1  ph7: (2i+3).Bh0  ph8: (2i+3).Bh1 +vm4
// Reads per tile window: ph1 A(qm0)+B(qn0), ph2 B(qn1), ph3 A(qm1), ph4 none
// (B(qn0) register-kept ph1->ph4; its LDS slot is overwritten ph3/ph4).
// ---------------------------------------------------------------------------
__device__ __forceinline__ void phase_mid() {
    asm volatile("" ::: "memory");
    __builtin_amdgcn_s_barrier();
    asm volatile("s_waitcnt lgkmcnt(0)" ::: "memory");
    __builtin_amdgcn_sched_barrier(0);
    __builtin_amdgcn_s_setprio(1);
}
__device__ __forceinline__ void phase_end() {
    __builtin_amdgcn_s_setprio(0);
    asm volatile("" ::: "memory");
    __builtin_amdgcn_s_barrier();
}

#define LOADA(d, qm) do {                                                     \
    char* s_ = lds + (d) * 65536 + ahalf * 16384;                             \
    _Pragma("unroll") for (int sm = 0; sm < 4; sm++)                          \
    _Pragma("unroll") for (int kk = 0; kk < 2; kk++) {                        \
        const int row_ = (qm) * 64 + sm * 16 + fr;                            \
        afr[sm][kk] = *(const bf16x8*)(s_ + row_ * 128 +                      \
                        (((kk * 4 + g) ^ (row_ & 7)) << 4));                  \
    } } while (0)

#define LOADB(d, qn, arr) do {                                                \
    char* s_ = lds + (d) * 65536 + 32768 + bhalf * 16384;                     \
    _Pragma("unroll") for (int sn = 0; sn < 2; sn++)                          \
    _Pragma("unroll") for (int kk = 0; kk < 2; kk++) {                        \
        const int row_ = brow0 + (qn) * 32 + sn * 16 + fr;                    \
        arr[sn][kk] = *(const bf16x8*)(s_ + row_ * 128 +                      \
                        (((kk * 4 + g) ^ (row_ & 7)) << 4));                  \
    } } while (0)

#define MFMA16(qm, qn, arr) do {                                              \
    _Pragma("unroll") for (int kk = 0; kk < 2; kk++)                          \
    _Pragma("unroll") for (int sm = 0; sm < 4; sm++)                          \
    _Pragma("unroll") for (int sn = 0; sn < 2; sn++)                          \
        acc[(qm) * 4 + sm][(qn) * 2 + sn] =                                   \
            __builtin_amdgcn_mfma_f32_16x16x32_bf16(afr[sm][kk], arr[sn][kk], \
                acc[(qm) * 4 + sm][(qn) * 2 + sn], 0, 0, 0);                  \
    } while (0)

template <bool OUTF32>
__global__ __launch_bounds__(512, 2)
void gemm_256(const bf16* __restrict__ A,
              const bf16* __restrict__ W0, const float* __restrict__ b0, void* O0,
              const bf16* __restrict__ W1, const float* __restrict__ b1, void* O1,
              const bf16* __restrict__ W2, const float* __restrict__ b2, void* O2,
              float snt)
{
    const int K = C_DIM, N = C_DIM;
    const int NT = K / 64;                       // 32 K-tiles, 16 iterations
    const bf16* W = W0; const float* bias = b0; void* Out = O0;
    if (blockIdx.z == 1)      { W = W1; bias = b1; Out = O1; }
    else if (blockIdx.z == 2) { W = W2; bias = b2; Out = O2; }

    __shared__ __attribute__((aligned(16))) char lds[131072];

    const int tid  = threadIdx.x;
    const int lane = tid & 63;
    const int w    = tid >> 6;

    // XCD chunk swizzle within the z-slice (128 wgs = 16m x 8n; each XCD owns
    // one n-strip x all m -> W panel L2-resident, A streams)
    int id = blockIdx.x + (int)gridDim.x * blockIdx.y;
    id = (id & 7) * 16 + (id >> 3);
    const int m0 = (id & 15) * 256;
    const int n0 = (id >> 4) * 256;

    const int wm = (w >> 2) * 128;               // wave M offset
    const int wn = (w & 3) * 64;                 // wave N offset
    const int fr = lane & 15;
    const int g  = lane >> 4;                    // k-group 0..3
    const int ahalf = w >> 2;                    // this wave's A half slot
    const int bhalf = (w >> 1) & 1;              // this wave's B half slot
    const int brow0 = (w & 1) * 64;              // row offset within B half

    // staging coords: thread t covers LDS linear byte t*16 of an 8KB issue;
    // source column pre-swizzled so swizzled ds_read returns correct data
    const int srow  = tid >> 3;                          // 0..63
    const int scol  = (((tid & 7) ^ (srow & 7)) * 8);    // swizzled col8
    const int wvoff = (tid >> 6) * 1024;

    f32x4 acc[8][4] = {};
    bf16x8 afr[4][2], b0r[2][2], b1r[2][2];

    #define STAGE_A(t, h) do {                                                \
        const int d_ = (t) & 1;                                               \
        const int tc_ = (t) < NT ? (t) : NT - 1;                              \
        const bf16* src_ = A + (size_t)(m0 + (h) * 128 + srow) * K            \
                             + tc_ * 64 + scol;                               \
        char* dst_ = lds + d_ * 65536 + (h) * 16384 + wvoff;                  \
        glds16(src_, dst_);                                                   \
        glds16(src_ + (size_t)64 * K, dst_ + 8192);                           \
    } while (0)

    #define STAGE_B(t, h) do {                                                \
        const int d_ = (t) & 1;                                               \
        const int tc_ = (t) < NT ? (t) : NT - 1;                              \
        const bf16* src_ = W + (size_t)(n0 + (h) * 128 + srow) * K            \
                             + tc_ * 64 + scol;                               \
        char* dst_ = lds + d_ * 65536 + 32768 + (h) * 16384 + wvoff;          \
        glds16(src_, dst_);                                                   \
        glds16(src_ + (size_t)64 * K, dst_ + 8192);                           \
    } while (0)

    // prologue: tile0 fully + tile1 B; leave tile1.B (4 loads) in flight
    STAGE_B(0, 0); STAGE_B(0, 1); STAGE_A(0, 0); STAGE_A(0, 1);
    STAGE_B(1, 0); STAGE_B(1, 1);
    asm volatile("s_waitcnt vmcnt(4)" ::: "memory");
    asm volatile("" ::: "memory");
    __builtin_amdgcn_s_barrier();

    #pragma unroll 1
    for (int i = 0; i < NT / 2; i++) {
        const int t1 = 2 * i + 1, t2 = 2 * i + 2, t3 = 2 * i + 3;
        // ph1
        LOADA(0, 0); LOADB(0, 0, b0r);
        STAGE_A(t1, 0);
        phase_mid(); MFMA16(0, 0, b0r); phase_end();
        // ph2
        LOADB(0, 1, b1r);
        STAGE_A(t1, 1);
        phase_mid(); MFMA16(0, 1, b1r); phase_end();
        // ph3
        LOADA(0, 1);
        STAGE_B(t2, 0);
        phase_mid(); MFMA16(1, 1, b1r); phase_end();
        // ph4
        STAGE_B(t2, 1);
        asm volatile("s_waitcnt vmcnt(4)" ::: "memory");
        phase_mid(); MFMA16(1, 0, b0r); phase_end();
        // ph5
        LOADA(1, 0); LOADB(1, 0, b0r);
        STAGE_A(t2, 0);
        phase_mid(); MFMA16(0, 0, b0r); phase_end();
        // ph6
        LOADB(1, 1, b1r);
        STAGE_A(t2, 1);
        phase_mid(); MFMA16(0, 1, b1r); phase_end();
        // ph7
        LOADA(1, 1);
        STAGE_B(t3, 0);
        phase_mid(); MFMA16(1, 1, b1r); phase_end();
        // ph8
        STAGE_B(t3, 1);
        asm volatile("s_waitcnt vmcnt(4)" ::: "memory");
        phase_mid(); MFMA16(1, 0, b0r); phase_end();
    }
    asm volatile("s_waitcnt vmcnt(0)" ::: "memory");

    // epilogue
    const int cn = lane & 15;
    const int r0 = (lane >> 4) * 4;
    #pragma unroll
    for (int sn2 = 0; sn2 < 4; sn2++) {
        const int n = n0 + wn + sn2 * 16 + cn;
        const float bv = bias[n];
        #pragma unroll
        for (int sm2 = 0; sm2 < 8; sm2++) {
            const int m = m0 + wm + sm2 * 16 + r0;
            #pragma unroll
            for (int r = 0; r < 4; r++) {
                const float v = san(acc[sm2][sn2][r] + bv, snt);
                if (OUTF32) ((float*)Out)[(size_t)(m + r) * N + n] = v;
                else        ((bf16*)Out)[(size_t)(m + r) * N + n] = (bf16)v;
            }
        }
    }
    #undef STAGE_A
    #undef STAGE_B
}

// ---------------------------------------------------------------------------
// one-shot fp32 -> bf16 conversion: seg 0 = x (8.4M), segs 1..4 = W (4.2M each)
// ---------------------------------------------------------------------------
__global__ __launch_bounds__(256)
void cvt_f32_bf16(const float* __restrict__ s0, bf16* __restrict__ d0,
                  const float* __restrict__ s1, bf16* __restrict__ d1,
                  const float* __restrict__ s2, bf16* __restrict__ d2,
                  const float* __restrict__ s3, bf16* __restrict__ d3,
                  const float* __restrict__ s4, bf16* __restrict__ d4)
{
    const float* s; bf16* d; int n;
    switch (blockIdx.y) {
        case 0:  s = s0; d = d0; n = M_ROWS * C_DIM; break;
        case 1:  s = s1; d = d1; n = C_DIM * C_DIM; break;
        case 2:  s = s2; d = d2; n = C_DIM * C_DIM; break;
        case 3:  s = s3; d = d3; n = C_DIM * C_DIM; break;
        default: s = s4; d = d4; n = C_DIM * C_DIM; break;
    }
    const int nv = n >> 3;
    const int stride = (int)gridDim.x * 256;
    for (int i = blockIdx.x * 256 + threadIdx.x; i < nv; i += stride) {
        const float4 lo = *(const float4*)(s + (size_t)i * 8);
        const float4 hi = *(const float4*)(s + (size_t)i * 8 + 4);
        *(bf16x8*)(d + (size_t)i * 8) = pack8(lo, hi);
    }
}

// ---------------------------------------------------------------------------
// Sliding-window causal attention, MFMA flash (verified r1). Unchanged.
// ---------------------------------------------------------------------------
#define SWZK(r, byteoff) ((((r) * 256) + (byteoff)) ^ (((r) & 7) << 4))
#define SWZV(d, byteoff) ((((d) * 128) + (byteoff)) ^ (((((d) & 7) ^ (((d) >> 3) & 7))) << 4))
#define SWZP(r, byteoff) ((((r) * 128) + (byteoff)) ^ (((r) & 7) << 4))

__global__ __launch_bounds__(256)
void swa_attn(const bf16* __restrict__ Q, const bf16* __restrict__ Kp,
              const bf16* __restrict__ V, bf16* __restrict__ Oattn, float snt)
{
    __shared__ bf16 Ks[64 * 128];
    __shared__ bf16 Vt[128 * 64];
    __shared__ bf16 Ps[64 * 64];

    const int tid  = threadIdx.x;
    const int lane = tid & 63;
    const int w    = tid >> 6;
    const int q0 = blockIdx.x * 64;
    const int h  = blockIdx.y;
    const int b  = blockIdx.z;
    const size_t base = (size_t)b * L_SEQ * C_DIM + (size_t)h * DH;

    const int fr  = lane & 15;
    const int g   = lane >> 4;
    const int fq8 = g * 8;

    bf16x8 qf[4];
    {
        const bf16* qrow = Q + base + (size_t)(q0 + w * 16 + fr) * C_DIM;
        #pragma unroll
        for (int kk = 0; kk < 4; kk++)
            qf[kk] = *(const bf16x8*)(qrow + kk * 32 + fq8);
    }

    const int rl0 = g * 4;
    const int ig  = q0 + w * 16 + rl0;
    const float scale = 0.08838834764831845f;

    float m_run[4], l_run[4];
    #pragma unroll
    for (int r = 0; r < 4; r++) { m_run[r] = -1e30f; l_run[r] = 0.0f; }
    f32x4 Oacc[8] = {};

    const int krr = tid >> 4;
    const int kcc = (tid & 15) * 8;
    const int vc  = tid & 15;
    const int vd0 = vc * 8;
    const int vpb = tid >> 4;

    for (int kb = 0; kb < 5; kb++) {
        const int s = q0 - 256 + kb * 64;
        if (s < 0) continue;

        __syncthreads();

        #pragma unroll
        for (int p = 0; p < 4; p++) {
            const int r = p * 16 + krr;
            const uint4 kv = *(const uint4*)(Kp + base + (size_t)(s + r) * C_DIM + kcc);
            *(uint4*)((char*)Ks + SWZK(r, kcc * 2)) = kv;
        }
        #pragma unroll
        for (int it = 0; it < 2; it++) {
            const int p = vpb + it * 16;
            const bf16* vr = V + base + (size_t)(s + 2 * p) * C_DIM + vd0;
            const u16x8 va = *(const u16x8*)vr;
            const u16x8 vb = *(const u16x8*)(vr + C_DIM);
            #pragma unroll
            for (int j = 0; j < 8; j++) {
                const uint32_t val = (uint32_t)va[j] | ((uint32_t)vb[j] << 16);
                *(uint32_t*)((char*)Vt + SWZV(vd0 + j, 4 * p)) = val;
            }
        }
        __syncthreads();

        f32x4 sacc[4] = {};
        __builtin_amdgcn_s_setprio(1);
        #pragma unroll
        for (int kk = 0; kk < 4; kk++) {
            #pragma unroll
            for (int t = 0; t < 4; t++) {
                const bf16x8 kf = *(const bf16x8*)((char*)Ks + SWZK(t * 16 + fr, (kk * 32 + fq8) * 2));
                sacc[t] = __builtin_amdgcn_mfma_f32_16x16x32_bf16(qf[kk], kf, sacc[t], 0, 0, 0);
            }
        }
        __builtin_amdgcn_s_setprio(0);

        float alpha[4];
        #pragma unroll
        for (int r = 0; r < 4; r++) {
            const int iq = ig + r;
            float p4[4];
            float bm = -1e30f;
            #pragma unroll
            for (int t = 0; t < 4; t++) {
                const int j = s + t * 16 + fr;
                const bool allow = (j <= iq) && (j > iq - WINSZ);
                p4[t] = allow ? sacc[t][r] * scale : -1e30f;
                bm = fmaxf(bm, p4[t]);
            }
            bm = fmaxf(bm, __shfl_xor(bm, 1, 64));
            bm = fmaxf(bm, __shfl_xor(bm, 2, 64));
            bm = fmaxf(bm, __shfl_xor(bm, 4, 64));
            bm = fmaxf(bm, __shfl_xor(bm, 8, 64));
            const float m_new = fmaxf(m_run[r], bm);
            alpha[r] = __expf(m_run[r] - m_new);
            m_run[r] = m_new;
            float ps = 0.0f;
            #pragma unroll
            for (int t = 0; t < 4; t++) {
                const float e = (p4[t] > -1e29f) ? __expf(p4[t] - m_new) : 0.0f;
                p4[t] = e;
                ps += e;
            }
            ps += __shfl_xor(ps, 1, 64);
            ps += __shfl_xor(ps, 2, 64);
            ps += __shfl_xor(ps, 4, 64);
            ps += __shfl_xor(ps, 8, 64);
            l_run[r] = l_run[r] * alpha[r] + ps;

            const int prow = w * 16 + rl0 + r;
            #pragma unroll
            for (int t = 0; t < 4; t++)
                *(bf16*)((char*)Ps + SWZP(prow, (t * 16 + fr) * 2)) = (bf16)p4[t];
        }

        #pragma unroll
        for (int t = 0; t < 8; t++)
            #pragma unroll
            for (int r = 0; r < 4; r++)
                Oacc[t][r] *= alpha[r];

        __builtin_amdgcn_s_setprio(1);
        #pragma unroll
        for (int kk = 0; kk < 2; kk++) {
            const bf16x8 pa = *(const bf16x8*)((char*)Ps + SWZP(w * 16 + fr, (kk * 32 + fq8) * 2));
            #pragma unroll
            for (int t = 0; t < 8; t++) {
                const bf16x8 vf = *(const bf16x8*)((char*)Vt + SWZV(t * 16 + fr, (kk * 32 + fq8) * 2));
                Oacc[t] = __builtin_amdgcn_mfma_f32_16x16x32_bf16(pa, vf, Oacc[t], 0, 0, 0);
            }
        }
        __builtin_amdgcn_s_setprio(0);
    }

    bf16* ob = Oattn + base;
    #pragma unroll
    for (int r = 0; r < 4; r++) {
        const float inv_l = 1.0f / l_run[r];
        const size_t ro = (size_t)(q0 + w * 16 + rl0 + r) * C_DIM;
        #pragma unroll
        for (int t = 0; t < 8; t++)
            ob[ro + t * 16 + fr] = (bf16)san(Oacc[t][r] * inv_l, snt);
    }
}

// layout-surprise signal (fp32 output)
__global__ void fill_signal(float* out, int n, float v) {
    for (int i = blockIdx.x * blockDim.x + threadIdx.x; i < n; i += gridDim.x * blockDim.x)
        out[i] = v;
}

// ---------------------------------------------------------------------------
extern "C" void kernel_launch(void* const* d_in, const int* in_sizes, int n_in,
                              void* d_out, int out_size, void* d_ws, size_t ws_size,
                              hipStream_t stream) {
    const size_t sz      = (size_t)M_ROWS * C_DIM;   // 8388608 elements
    const size_t wsz     = (size_t)C_DIM * C_DIM;    // 4194304 elements
    const size_t bfbytes = sz * sizeof(bf16);        // 16.78 MB
    const size_t FASTNEED = 3 * sz * sizeof(bf16) + 4 * wsz * sizeof(bf16); // 80 MB

    const int expn[9] = {8388608, 4194304, 2048, 4194304, 2048,
                         4194304, 2048, 4194304, 2048};
    float sig = 0.0f;
    if (n_in != 9) sig = 1100.0f;
    else {
        for (int i = 0; i < 9; i++)
            if (in_sizes[i] != expn[i]) { sig = 1200.0f + 100.0f * i; break; }
    }
    if (sig == 0.0f && out_size != (int)sz) sig = 2100.0f;
    if (sig == 0.0f && ws_size < 2 * bfbytes) sig = 3000.0f + 10.0f * (float)(ws_size >> 20);
    if (sig != 0.0f) {
        fill_signal<<<512, 256, 0, stream>>>((float*)d_out, (int)sz, sig);
        return;
    }

    const float* x  = (const float*)d_in[0];
    const float* Wq = (const float*)d_in[1];
    const float* bq = (const float*)d_in[2];
    const float* Wk = (const float*)d_in[3];
    const float* bk = (const float*)d_in[4];
    const float* Wv = (const float*)d_in[5];
    const float* bv = (const float*)d_in[6];
    const float* Wo = (const float*)d_in[7];
    const float* bo = (const float*)d_in[8];

    if (ws_size >= FASTNEED) {
        // ---------------- fast path ----------------
        bf16* xbf = (bf16*)d_ws;          // x bf16; later reused as O_att
        bf16* kws = xbf + sz;             // K
        bf16* vws = kws + sz;             // V
        bf16* wqb = vws + sz;             // W bf16 x4
        bf16* wkb = wqb + wsz;
        bf16* wvb = wkb + wsz;
        bf16* wob = wvb + wsz;
        bf16*  qscr  = (bf16*)d_out;      // Q bf16 in d_out's first half
        float* out32 = (float*)d_out;

        // 0) fp32 -> bf16 one-shot conversions
        cvt_f32_bf16<<<dim3(2048, 5), 256, 0, stream>>>(
            x, xbf, Wq, wqb, Wk, wkb, Wv, wvb, Wo, wob);

        // 1) QKV projections (8-phase 256^2 GEMM)
        gemm_256<false><<<dim3(16, 8, 3), 512, 0, stream>>>(
            xbf, wqb, bq, (void*)qscr, wkb, bk, (void*)kws,
            wvb, bv, (void*)vws, 111.0f);

        // 2) attention; O_att -> dead xbf region
        swa_attn<<<dim3(L_SEQ / 64, NHEAD, NBATCH), 256, 0, stream>>>(
            qscr, kws, vws, xbf, 222.0f);

        // 3) output projection (fp32 out), full d_out overwrite
        gemm_256<true><<<dim3(16, 8, 1), 512, 0, stream>>>(
            xbf, wob, bo, (void*)out32, wob, bo, (void*)out32,
            wob, bo, (void*)out32, 444.0f);
    } else {
        // ---------------- slow path: r1-verified flow ----------------
        bf16*  kws   = (bf16*)d_ws;
        bf16*  vws   = kws + sz;
        bf16*  qscr  = (bf16*)d_out;
        float* out32 = (float*)d_out;

        gemm_bt_bias<true, false><<<dim3(32, 16, 3), 256, 0, stream>>>(
            (const void*)x, Wq, bq, (void*)qscr, Wk, bk, (void*)kws,
            Wv, bv, (void*)vws, 111.0f);

        swa_attn<<<dim3(L_SEQ / 64, NHEAD, NBATCH), 256, 0, stream>>>(
            qscr, kws, vws, qscr, 222.0f);

        hipMemcpyAsync(kws, qscr, bfbytes, hipMemcpyDeviceToDevice, stream);

        gemm_bt_bias<false, true><<<dim3(32, 16, 1), 256, 0, stream>>>(
            (const void*)kws, Wo, bo, (void*)out32, Wo, bo, (void*)out32,
            Wo, bo, (void*)out32, 444.0f);
    }
}

// Round 4
// 329.520 us; speedup vs baseline: 1.9798x; 1.0919x over previous
//
#include <hip/hip_runtime.h>
#include <hip/hip_bf16.h>
#include <stdint.h>

typedef __bf16 bf16;
typedef __attribute__((ext_vector_type(8))) __bf16 bf16x8;
typedef __attribute__((ext_vector_type(8))) unsigned short u16x8;
typedef __attribute__((ext_vector_type(4))) float f32x4;

#define L_SEQ 2048
#define C_DIM 2048
#define NBATCH 2
#define M_ROWS (NBATCH * L_SEQ)   // 4096
#define DH 128
#define NHEAD 16
#define WINSZ 256

__device__ __forceinline__ float san(float v, float s) {
    return ((__float_as_uint(v) & 0x7f800000u) == 0x7f800000u) ? s : v;
}

__device__ __forceinline__ bf16x8 pack8(float4 lo, float4 hi) {
    bf16x8 v;
    v[0] = (bf16)lo.x; v[1] = (bf16)lo.y; v[2] = (bf16)lo.z; v[3] = (bf16)lo.w;
    v[4] = (bf16)hi.x; v[5] = (bf16)hi.y; v[6] = (bf16)hi.z; v[7] = (bf16)hi.w;
    return v;
}

typedef const __attribute__((address_space(1))) void g_void;
typedef __attribute__((address_space(3))) void l_void;
__device__ __forceinline__ void glds16(const void* g, void* l) {
    __builtin_amdgcn_global_load_lds((g_void*)g, (l_void*)l, 16, 0, 0);
}

// ---------------------------------------------------------------------------
// SLOW-PATH GEMM (reg-staged) — fallback when workspace is small. Verified.
// ---------------------------------------------------------------------------
template <bool AF32, bool OUTF32>
__global__ __launch_bounds__(256)
void gemm_bt_bias(const void* __restrict__ Ap,
                  const float* __restrict__ W0, const float* __restrict__ b0, void* O0,
                  const float* __restrict__ W1, const float* __restrict__ b1, void* O1,
                  const float* __restrict__ W2, const float* __restrict__ b2, void* O2,
                  float snt)
{
    const int K = C_DIM, N = C_DIM;
    const float* W = W0; const float* bias = b0; void* Out = O0;
    if (blockIdx.z == 1)      { W = W1; bias = b1; Out = O1; }
    else if (blockIdx.z == 2) { W = W2; bias = b2; Out = O2; }

    __shared__ bf16 As[128 * 32];
    __shared__ bf16 Bs[128 * 32];

    const int tid  = threadIdx.x;
    const int lane = tid & 63;
    const int m0 = blockIdx.x * 128;
    const int n0 = blockIdx.y * 128;

    const int wave = tid >> 6;
    const int wm = (wave >> 1) * 64;
    const int wn = (wave & 1) * 64;

    const int srow = tid >> 2;
    const int scol = (tid & 3) * 8;

    f32x4 acc[4][4] = {};

    const int fr = lane & 15;
    const int fq = (lane >> 4) * 8;

    for (int k0 = 0; k0 < K; k0 += 32) {
        bf16x8 ra[2], rb[2];
        #pragma unroll
        for (int p = 0; p < 2; p++) {
            const size_t aoff = (size_t)(m0 + p * 64 + srow) * K + k0 + scol;
            if (AF32) {
                const float* A = (const float*)Ap;
                float4 lo = *(const float4*)(A + aoff);
                float4 hi = *(const float4*)(A + aoff + 4);
                ra[p] = pack8(lo, hi);
            } else {
                const bf16* A = (const bf16*)Ap;
                ra[p] = *(const bf16x8*)(A + aoff);
            }
            const size_t boff = (size_t)(n0 + p * 64 + srow) * K + k0 + scol;
            float4 wlo = *(const float4*)(W + boff);
            float4 whi = *(const float4*)(W + boff + 4);
            rb[p] = pack8(wlo, whi);
        }
        __syncthreads();
        #pragma unroll
        for (int p = 0; p < 2; p++) {
            *(bf16x8*)&As[(p * 64 + srow) * 32 + scol] = ra[p];
            *(bf16x8*)&Bs[(p * 64 + srow) * 32 + scol] = rb[p];
        }
        __syncthreads();

        bf16x8 af[4], bfr[4];
        #pragma unroll
        for (int s = 0; s < 4; s++)
            af[s] = *(const bf16x8*)&As[(wm + s * 16 + fr) * 32 + fq];
        #pragma unroll
        for (int s = 0; s < 4; s++)
            bfr[s] = *(const bf16x8*)&Bs[(wn + s * 16 + fr) * 32 + fq];
        #pragma unroll
        for (int sm = 0; sm < 4; sm++)
            #pragma unroll
            for (int sn = 0; sn < 4; sn++)
                acc[sm][sn] = __builtin_amdgcn_mfma_f32_16x16x32_bf16(af[sm], bfr[sn], acc[sm][sn], 0, 0, 0);
    }

    const int r0 = (lane >> 4) * 4;
    const int cn = lane & 15;
    #pragma unroll
    for (int sn = 0; sn < 4; sn++) {
        const int n = n0 + wn + sn * 16 + cn;
        const float bv = bias[n];
        #pragma unroll
        for (int sm = 0; sm < 4; sm++) {
            const int m = m0 + wm + sm * 16 + r0;
            #pragma unroll
            for (int r = 0; r < 4; r++) {
                const float v = san(acc[sm][sn][r] + bv, snt);
                if (OUTF32) ((float*)Out)[(size_t)(m + r) * N + n] = v;
                else        ((bf16*)Out)[(size_t)(m + r) * N + n] = (bf16)v;
            }
        }
    }
}

// ---------------------------------------------------------------------------
// FAST GEMM: 256x128 tile, BK=64, 8 waves (4M x 2N, wave tile 64x64),
// 4-phase iteration over 2 K-tiles, counted vmcnt(4) (never 0 in-loop),
// double-buffered 96KB LDS, T2 chunk-swizzle (pre-swizzled global source +
// swizzled ds_read), T5 setprio. Grid exact-round: QKV 768 blocks = 3 rounds,
// Wo 256 blocks = 1 round (fixes r3's 1.5-round / 0.5-round tail waste).
//
// Slot map per buf d (48KB @ d*49152): A rows 0-255 [0,32K) (halves 16K),
// B rows 0-127 [32K,48K). Rows 128B, chunk c placed at c^(row&7).
// Stage schedule per iteration i (tiles 2i buf0, 2i+1 buf1):
//   ph1: B(2i+1) [2 iss]   ph2: A(2i+2) [4 iss] +vmcnt(4)
//   ph3: B(2i+2) [2 iss]   ph4: A(2i+3) [4 iss] +vmcnt(4)
// FIFO proof: ph2 vmcnt(4) retires A(t1)+B(t1) (needed by ph3/ph4 reads);
// ph4 vmcnt(4) retires A(t2)+B(t2) (needed by next ph1/ph2 reads).
// ---------------------------------------------------------------------------
__device__ __forceinline__ void phase_mid() {
    asm volatile("" ::: "memory");
    __builtin_amdgcn_s_barrier();
    asm volatile("s_waitcnt lgkmcnt(0)" ::: "memory");
    __builtin_amdgcn_sched_barrier(0);
    __builtin_amdgcn_s_setprio(1);
}
__device__ __forceinline__ void phase_end() {
    __builtin_amdgcn_s_setprio(0);
    asm volatile("" ::: "memory");
    __builtin_amdgcn_s_barrier();
}

#define BUFSZ 49152
#define BOFF  32768

#define LDA2(d) do {                                                          \
    char* s_ = lds + (d) * BUFSZ + ahalf * 16384;                             \
    _Pragma("unroll") for (int sm = 0; sm < 4; sm++)                          \
    _Pragma("unroll") for (int kk = 0; kk < 2; kk++) {                        \
        const int row_ = arow0 + sm * 16 + fr;                                \
        afr[sm][kk] = *(const bf16x8*)(s_ + row_ * 128 +                      \
                        (((kk * 4 + g) ^ (row_ & 7)) << 4));                  \
    } } while (0)

#define LDB2(d, qn, arr) do {                                                 \
    char* s_ = lds + (d) * BUFSZ + BOFF;                                      \
    _Pragma("unroll") for (int sn = 0; sn < 2; sn++)                          \
    _Pragma("unroll") for (int kk = 0; kk < 2; kk++) {                        \
        const int row_ = wn + (qn) * 32 + sn * 16 + fr;                       \
        arr[sn][kk] = *(const bf16x8*)(s_ + row_ * 128 +                      \
                        (((kk * 4 + g) ^ (row_ & 7)) << 4));                  \
    } } while (0)

#define MFMAH(qn, arr) do {                                                   \
    _Pragma("unroll") for (int kk = 0; kk < 2; kk++)                          \
    _Pragma("unroll") for (int sm = 0; sm < 4; sm++)                          \
    _Pragma("unroll") for (int sn = 0; sn < 2; sn++)                          \
        acc[sm][(qn) * 2 + sn] =                                              \
            __builtin_amdgcn_mfma_f32_16x16x32_bf16(afr[sm][kk], arr[sn][kk], \
                acc[sm][(qn) * 2 + sn], 0, 0, 0);                             \
    } while (0)

template <bool OUTF32>
__global__ __launch_bounds__(512, 2)
void gemm_256x128(const bf16* __restrict__ A,
                  const bf16* __restrict__ W0, const float* __restrict__ b0, void* O0,
                  const bf16* __restrict__ W1, const float* __restrict__ b1, void* O1,
                  const bf16* __restrict__ W2, const float* __restrict__ b2, void* O2,
                  float snt)
{
    const int K = C_DIM, N = C_DIM;
    const int NT = K / 64;                       // 32 K-tiles, 16 iterations
    const bf16* W = W0; const float* bias = b0; void* Out = O0;
    if (blockIdx.z == 1)      { W = W1; bias = b1; Out = O1; }
    else if (blockIdx.z == 2) { W = W2; bias = b2; Out = O2; }

    __shared__ __attribute__((aligned(16))) char lds[98304];

    const int tid  = threadIdx.x;
    const int lane = tid & 63;
    const int w    = tid >> 6;

    // XCD chunk swizzle, bijective (256 wgs per z-slice, 256 % 8 == 0)
    int id = blockIdx.x + (int)gridDim.x * blockIdx.y;
    id = (id & 7) * 32 + (id >> 3);
    const int m0 = (id & 15) * 256;
    const int n0 = (id >> 4) * 128;

    const int wm = (w >> 1) * 64;                // wave M offset 0/64/128/192
    const int wn = (w & 1) * 64;                 // wave N offset 0/64
    const int fr = lane & 15;
    const int g  = lane >> 4;
    const int ahalf = w >> 2;                    // A half slot
    const int arow0 = ((w >> 1) & 1) * 64;       // row offset within half

    const int srow  = tid >> 3;                          // 0..63
    const int scol  = (((tid & 7) ^ (srow & 7)) * 8);    // pre-swizzled col8
    const int wvoff = (tid >> 6) * 1024;

    f32x4 acc[4][4] = {};
    bf16x8 afr[4][2], b0r[2][2], b1r[2][2];

    #define STAGE_A(t) do {                                                   \
        const int d_ = (t) & 1;                                               \
        const int tc_ = (t) < NT ? (t) : NT - 1;                              \
        const bf16* src_ = A + (size_t)(m0 + srow) * K + tc_ * 64 + scol;     \
        char* dst_ = lds + d_ * BUFSZ + wvoff;                                \
        glds16(src_,                   dst_);                                 \
        glds16(src_ + (size_t)64 * K,  dst_ + 8192);                          \
        glds16(src_ + (size_t)128 * K, dst_ + 16384);                         \
        glds16(src_ + (size_t)192 * K, dst_ + 24576);                         \
    } while (0)

    #define STAGE_B(t) do {                                                   \
        const int d_ = (t) & 1;                                               \
        const int tc_ = (t) < NT ? (t) : NT - 1;                              \
        const bf16* src_ = W + (size_t)(n0 + srow) * K + tc_ * 64 + scol;     \
        char* dst_ = lds + d_ * BUFSZ + BOFF + wvoff;                         \
        glds16(src_,                  dst_);                                  \
        glds16(src_ + (size_t)64 * K, dst_ + 8192);                           \
    } while (0)

    // prologue: tile0 fully + tile1 A; leave tile1.A (4 issues) in flight
    STAGE_A(0); STAGE_B(0); STAGE_A(1);
    asm volatile("s_waitcnt vmcnt(4)" ::: "memory");
    asm volatile("" ::: "memory");
    __builtin_amdgcn_s_barrier();

    #pragma unroll 1
    for (int i = 0; i < NT / 2; i++) {
        const int t1 = 2 * i + 1, t2 = 2 * i + 2, t3 = 2 * i + 3;
        // ph1: buf0 cols [wn, wn+32)
        LDA2(0); LDB2(0, 0, b0r);
        STAGE_B(t1);
        phase_mid(); MFMAH(0, b0r); phase_end();
        // ph2: buf0 cols [wn+32, wn+64)
        LDB2(0, 1, b1r);
        STAGE_A(t2);
        asm volatile("s_waitcnt vmcnt(4)" ::: "memory");
        phase_mid(); MFMAH(1, b1r); phase_end();
        // ph3: buf1 cols [wn, wn+32)
        LDA2(1); LDB2(1, 0, b0r);
        STAGE_B(t2);
        phase_mid(); MFMAH(0, b0r); phase_end();
        // ph4: buf1 cols [wn+32, wn+64)
        LDB2(1, 1, b1r);
        STAGE_A(t3);
        asm volatile("s_waitcnt vmcnt(4)" ::: "memory");
        phase_mid(); MFMAH(1, b1r); phase_end();
    }
    asm volatile("s_waitcnt vmcnt(0)" ::: "memory");

    // epilogue: C/D layout col=lane&15, row=(lane>>4)*4+reg (m89-verified)
    const int cn = lane & 15;
    const int r0 = (lane >> 4) * 4;
    #pragma unroll
    for (int sn2 = 0; sn2 < 4; sn2++) {
        const int n = n0 + wn + sn2 * 16 + cn;
        const float bv = bias[n];
        #pragma unroll
        for (int sm2 = 0; sm2 < 4; sm2++) {
            const int m = m0 + wm + sm2 * 16 + r0;
            #pragma unroll
            for (int r = 0; r < 4; r++) {
                const float v = san(acc[sm2][sn2][r] + bv, snt);
                if (OUTF32) ((float*)Out)[(size_t)(m + r) * N + n] = v;
                else        ((bf16*)Out)[(size_t)(m + r) * N + n] = (bf16)v;
            }
        }
    }
    #undef STAGE_A
    #undef STAGE_B
}

// ---------------------------------------------------------------------------
// one-shot fp32 -> bf16 conversion: seg 0 = x (8.4M), segs 1..4 = W (4.2M each)
// ---------------------------------------------------------------------------
__global__ __launch_bounds__(256)
void cvt_f32_bf16(const float* __restrict__ s0, bf16* __restrict__ d0,
                  const float* __restrict__ s1, bf16* __restrict__ d1,
                  const float* __restrict__ s2, bf16* __restrict__ d2,
                  const float* __restrict__ s3, bf16* __restrict__ d3,
                  const float* __restrict__ s4, bf16* __restrict__ d4)
{
    const float* s; bf16* d; int n;
    switch (blockIdx.y) {
        case 0:  s = s0; d = d0; n = M_ROWS * C_DIM; break;
        case 1:  s = s1; d = d1; n = C_DIM * C_DIM; break;
        case 2:  s = s2; d = d2; n = C_DIM * C_DIM; break;
        case 3:  s = s3; d = d3; n = C_DIM * C_DIM; break;
        default: s = s4; d = d4; n = C_DIM * C_DIM; break;
    }
    const int nv = n >> 3;
    const int stride = (int)gridDim.x * 256;
    for (int i = blockIdx.x * 256 + threadIdx.x; i < nv; i += stride) {
        const float4 lo = *(const float4*)(s + (size_t)i * 8);
        const float4 hi = *(const float4*)(s + (size_t)i * 8 + 4);
        *(bf16x8*)(d + (size_t)i * 8) = pack8(lo, hi);
    }
}

// ---------------------------------------------------------------------------
// Sliding-window causal attention, MFMA flash (verified r1). Unchanged.
// ---------------------------------------------------------------------------
#define SWZK(r, byteoff) ((((r) * 256) + (byteoff)) ^ (((r) & 7) << 4))
#define SWZV(d, byteoff) ((((d) * 128) + (byteoff)) ^ (((((d) & 7) ^ (((d) >> 3) & 7))) << 4))
#define SWZP(r, byteoff) ((((r) * 128) + (byteoff)) ^ (((r) & 7) << 4))

__global__ __launch_bounds__(256)
void swa_attn(const bf16* __restrict__ Q, const bf16* __restrict__ Kp,
              const bf16* __restrict__ V, bf16* __restrict__ Oattn, float snt)
{
    __shared__ bf16 Ks[64 * 128];
    __shared__ bf16 Vt[128 * 64];
    __shared__ bf16 Ps[64 * 64];

    const int tid  = threadIdx.x;
    const int lane = tid & 63;
    const int w    = tid >> 6;
    const int q0 = blockIdx.x * 64;
    const int h  = blockIdx.y;
    const int b  = blockIdx.z;
    const size_t base = (size_t)b * L_SEQ * C_DIM + (size_t)h * DH;

    const int fr  = lane & 15;
    const int g   = lane >> 4;
    const int fq8 = g * 8;

    bf16x8 qf[4];
    {
        const bf16* qrow = Q + base + (size_t)(q0 + w * 16 + fr) * C_DIM;
        #pragma unroll
        for (int kk = 0; kk < 4; kk++)
            qf[kk] = *(const bf16x8*)(qrow + kk * 32 + fq8);
    }

    const int rl0 = g * 4;
    const int ig  = q0 + w * 16 + rl0;
    const float scale = 0.08838834764831845f;

    float m_run[4], l_run[4];
    #pragma unroll
    for (int r = 0; r < 4; r++) { m_run[r] = -1e30f; l_run[r] = 0.0f; }
    f32x4 Oacc[8] = {};

    const int krr = tid >> 4;
    const int kcc = (tid & 15) * 8;
    const int vc  = tid & 15;
    const int vd0 = vc * 8;
    const int vpb = tid >> 4;

    for (int kb = 0; kb < 5; kb++) {
        const int s = q0 - 256 + kb * 64;
        if (s < 0) continue;

        __syncthreads();

        #pragma unroll
        for (int p = 0; p < 4; p++) {
            const int r = p * 16 + krr;
            const uint4 kv = *(const uint4*)(Kp + base + (size_t)(s + r) * C_DIM + kcc);
            *(uint4*)((char*)Ks + SWZK(r, kcc * 2)) = kv;
        }
        #pragma unroll
        for (int it = 0; it < 2; it++) {
            const int p = vpb + it * 16;
            const bf16* vr = V + base + (size_t)(s + 2 * p) * C_DIM + vd0;
            const u16x8 va = *(const u16x8*)vr;
            const u16x8 vb = *(const u16x8*)(vr + C_DIM);
            #pragma unroll
            for (int j = 0; j < 8; j++) {
                const uint32_t val = (uint32_t)va[j] | ((uint32_t)vb[j] << 16);
                *(uint32_t*)((char*)Vt + SWZV(vd0 + j, 4 * p)) = val;
            }
        }
        __syncthreads();

        f32x4 sacc[4] = {};
        __builtin_amdgcn_s_setprio(1);
        #pragma unroll
        for (int kk = 0; kk < 4; kk++) {
            #pragma unroll
            for (int t = 0; t < 4; t++) {
                const bf16x8 kf = *(const bf16x8*)((char*)Ks + SWZK(t * 16 + fr, (kk * 32 + fq8) * 2));
                sacc[t] = __builtin_amdgcn_mfma_f32_16x16x32_bf16(qf[kk], kf, sacc[t], 0, 0, 0);
            }
        }
        __builtin_amdgcn_s_setprio(0);

        float alpha[4];
        #pragma unroll
        for (int r = 0; r < 4; r++) {
            const int iq = ig + r;
            float p4[4];
            float bm = -1e30f;
            #pragma unroll
            for (int t = 0; t < 4; t++) {
                const int j = s + t * 16 + fr;
                const bool allow = (j <= iq) && (j > iq - WINSZ);
                p4[t] = allow ? sacc[t][r] * scale : -1e30f;
                bm = fmaxf(bm, p4[t]);
            }
            bm = fmaxf(bm, __shfl_xor(bm, 1, 64));
            bm = fmaxf(bm, __shfl_xor(bm, 2, 64));
            bm = fmaxf(bm, __shfl_xor(bm, 4, 64));
            bm = fmaxf(bm, __shfl_xor(bm, 8, 64));
            const float m_new = fmaxf(m_run[r], bm);
            alpha[r] = __expf(m_run[r] - m_new);
            m_run[r] = m_new;
            float ps = 0.0f;
            #pragma unroll
            for (int t = 0; t < 4; t++) {
                const float e = (p4[t] > -1e29f) ? __expf(p4[t] - m_new) : 0.0f;
                p4[t] = e;
                ps += e;
            }
            ps += __shfl_xor(ps, 1, 64);
            ps += __shfl_xor(ps, 2, 64);
            ps += __shfl_xor(ps, 4, 64);
            ps += __shfl_xor(ps, 8, 64);
            l_run[r] = l_run[r] * alpha[r] + ps;

            const int prow = w * 16 + rl0 + r;
            #pragma unroll
            for (int t = 0; t < 4; t++)
                *(bf16*)((char*)Ps + SWZP(prow, (t * 16 + fr) * 2)) = (bf16)p4[t];
        }

        #pragma unroll
        for (int t = 0; t < 8; t++)
            #pragma unroll
            for (int r = 0; r < 4; r++)
                Oacc[t][r] *= alpha[r];

        __builtin_amdgcn_s_setprio(1);
        #pragma unroll
        for (int kk = 0; kk < 2; kk++) {
            const bf16x8 pa = *(const bf16x8*)((char*)Ps + SWZP(w * 16 + fr, (kk * 32 + fq8) * 2));
            #pragma unroll
            for (int t = 0; t < 8; t++) {
                const bf16x8 vf = *(const bf16x8*)((char*)Vt + SWZV(t * 16 + fr, (kk * 32 + fq8) * 2));
                Oacc[t] = __builtin_amdgcn_mfma_f32_16x16x32_bf16(pa, vf, Oacc[t], 0, 0, 0);
            }
        }
        __builtin_amdgcn_s_setprio(0);
    }

    bf16* ob = Oattn + base;
    #pragma unroll
    for (int r = 0; r < 4; r++) {
        const float inv_l = 1.0f / l_run[r];
        const size_t ro = (size_t)(q0 + w * 16 + rl0 + r) * C_DIM;
        #pragma unroll
        for (int t = 0; t < 8; t++)
            ob[ro + t * 16 + fr] = (bf16)san(Oacc[t][r] * inv_l, snt);
    }
}

// layout-surprise signal (fp32 output)
__global__ void fill_signal(float* out, int n, float v) {
    for (int i = blockIdx.x * blockDim.x + threadIdx.x; i < n; i += gridDim.x * blockDim.x)
        out[i] = v;
}

// ---------------------------------------------------------------------------
extern "C" void kernel_launch(void* const* d_in, const int* in_sizes, int n_in,
                              void* d_out, int out_size, void* d_ws, size_t ws_size,
                              hipStream_t stream) {
    const size_t sz      = (size_t)M_ROWS * C_DIM;   // 8388608 elements
    const size_t wsz     = (size_t)C_DIM * C_DIM;    // 4194304 elements
    const size_t bfbytes = sz * sizeof(bf16);        // 16.78 MB
    const size_t FASTNEED = 3 * sz * sizeof(bf16) + 4 * wsz * sizeof(bf16); // 80 MB

    const int expn[9] = {8388608, 4194304, 2048, 4194304, 2048,
                         4194304, 2048, 4194304, 2048};
    float sig = 0.0f;
    if (n_in != 9) sig = 1100.0f;
    else {
        for (int i = 0; i < 9; i++)
            if (in_sizes[i] != expn[i]) { sig = 1200.0f + 100.0f * i; break; }
    }
    if (sig == 0.0f && out_size != (int)sz) sig = 2100.0f;
    if (sig == 0.0f && ws_size < 2 * bfbytes) sig = 3000.0f + 10.0f * (float)(ws_size >> 20);
    if (sig != 0.0f) {
        fill_signal<<<512, 256, 0, stream>>>((float*)d_out, (int)sz, sig);
        return;
    }

    const float* x  = (const float*)d_in[0];
    const float* Wq = (const float*)d_in[1];
    const float* bq = (const float*)d_in[2];
    const float* Wk = (const float*)d_in[3];
    const float* bk = (const float*)d_in[4];
    const float* Wv = (const float*)d_in[5];
    const float* bv = (const float*)d_in[6];
    const float* Wo = (const float*)d_in[7];
    const float* bo = (const float*)d_in[8];

    if (ws_size >= FASTNEED) {
        // ---------------- fast path ----------------
        bf16* xbf = (bf16*)d_ws;          // x bf16; later reused as O_att
        bf16* kws = xbf + sz;             // K
        bf16* vws = kws + sz;             // V
        bf16* wqb = vws + sz;             // W bf16 x4
        bf16* wkb = wqb + wsz;
        bf16* wvb = wkb + wsz;
        bf16* wob = wvb + wsz;
        bf16*  qscr  = (bf16*)d_out;      // Q bf16 in d_out's first half
        float* out32 = (float*)d_out;

        // 0) fp32 -> bf16 one-shot conversions
        cvt_f32_bf16<<<dim3(2048, 5), 256, 0, stream>>>(
            x, xbf, Wq, wqb, Wk, wkb, Wv, wvb, Wo, wob);

        // 1) QKV projections: 768 blocks = 3 exact rounds
        gemm_256x128<false><<<dim3(16, 16, 3), 512, 0, stream>>>(
            xbf, wqb, bq, (void*)qscr, wkb, bk, (void*)kws,
            wvb, bv, (void*)vws, 111.0f);

        // 2) attention; O_att -> dead xbf region
        swa_attn<<<dim3(L_SEQ / 64, NHEAD, NBATCH), 256, 0, stream>>>(
            qscr, kws, vws, xbf, 222.0f);

        // 3) output projection: 256 blocks = 1 exact round
        gemm_256x128<true><<<dim3(16, 16, 1), 512, 0, stream>>>(
            xbf, wob, bo, (void*)out32, wob, bo, (void*)out32,
            wob, bo, (void*)out32, 444.0f);
    } else {
        // ---------------- slow path: r1-verified flow ----------------
        bf16*  kws   = (bf16*)d_ws;
        bf16*  vws   = kws + sz;
        bf16*  qscr  = (bf16*)d_out;
        float* out32 = (float*)d_out;

        gemm_bt_bias<true, false><<<dim3(32, 16, 3), 256, 0, stream>>>(
            (const void*)x, Wq, bq, (void*)qscr, Wk, bk, (void*)kws,
            Wv, bv, (void*)vws, 111.0f);

        swa_attn<<<dim3(L_SEQ / 64, NHEAD, NBATCH), 256, 0, stream>>>(
            qscr, kws, vws, qscr, 222.0f);

        hipMemcpyAsync(kws, qscr, bfbytes, hipMemcpyDeviceToDevice, stream);

        gemm_bt_bias<false, true><<<dim3(32, 16, 1), 256, 0, stream>>>(
            (const void*)kws, Wo, bo, (void*)out32, Wo, bo, (void*)out32,
            Wo, bo, (void*)out32, 444.0f);
    }
}